// Round 3
// baseline (186.075 us; speedup 1.0000x reference)
//
#include <hip/hip_runtime.h>
#include <hip/hip_bf16.h>

#define NSAMP 128
#define AGENTS 64
#define D 128
#define NN (NSAMP * AGENTS)      // 8192
#define LOG2E 1.44269504088896340736f
#define LN2   0.69314718055994530942f
#define EPSF  1e-5f

// ---------------------------------------------------------------------------
// Kernel 1: per-node linear terms, exponentiated.
//   arr 0: EAf = exp2(-log2e*(x@Wf[0:128]   + c@Wf[256:258] + bf))
//   arr 1: EBf = exp2(-log2e*(x@Wf[128:256] - c@Wf[256:258]))
//   arr 2: EAs = exp2(+log2e*(x@Ws[0:128]   + c@Ws[256:258] + bs))
//   arr 3: EBs = exp2(+log2e*(x@Ws[128:256] - c@Ws[256:258]))
// grid = 64 mtiles(128 rows) x 4 arrays(128 cols); block 256; micro 8x8 with
// split row/col groups (+64) so W-reads are 16B-contiguous (2-way = free) and
// A-reads are 4-address broadcasts. K=128 staged once -> single barrier.
// Optional fused BN of the PREVIOUS layer while staging X:
//   xnew = relu((agg-mu)*rstd*gamma + beta + xold); arr==0 blocks write x1out.
// ---------------------------------------------------------------------------
__global__ __launch_bounds__(256) void prep_kernel(
    const float* __restrict__ x,        // [NN][D] (pre-BN input when fused)
    const float* __restrict__ centers,  // [NN][2]
    const float* __restrict__ Wf,       // [258][D]
    const float* __restrict__ bf,       // [D]
    const float* __restrict__ Ws,       // [258][D]
    const float* __restrict__ bs,       // [D]
    const float* __restrict__ agg,      // [NN][D] or nullptr (no fused BN)
    const float* __restrict__ stats,    // [2][D] mu,rstd (when fused)
    const float* __restrict__ gamma, const float* __restrict__ beta,
    float* __restrict__ x1out,          // fused: post-BN x written by arr==0
    float* __restrict__ out)            // 4 x [NN][D]: EAf,EBf,EAs,EBs
{
    const int mt  = blockIdx.x >> 2;
    const int arr = blockIdx.x & 3;
    const int m0  = mt * 128;
    const int tid = threadIdx.x;
    const float* Wsrc  = (arr < 2) ? Wf : Ws;
    const int    rowoff = (arr & 1) ? D : 0;
    const bool   fuse  = (agg != nullptr);

    __shared__ float Xs[128][132];      // row stride 528B (16B-aligned)
    __shared__ float Wt[128][128];

    // stage X tile 128x128 (optionally applying previous layer's BN+res+relu)
    #pragma unroll
    for (int i = 0; i < 16; ++i) {
        int f4 = i * 256 + tid;
        int idx = f4 * 4;
        int m = idx >> 7, k = idx & 127;
        size_t goff = (size_t)(m0 + m) * D + k;
        float4 v = *(const float4*)&x[goff];
        if (fuse) {
            float4 a  = *(const float4*)&agg[goff];
            float4 mu = *(const float4*)&stats[k];
            float4 rs = *(const float4*)&stats[D + k];
            float4 gm = *(const float4*)&gamma[k];
            float4 bt = *(const float4*)&beta[k];
            v.x = fmaxf(0.f, fmaf((a.x - mu.x) * rs.x, gm.x, bt.x) + v.x);
            v.y = fmaxf(0.f, fmaf((a.y - mu.y) * rs.y, gm.y, bt.y) + v.y);
            v.z = fmaxf(0.f, fmaf((a.z - mu.z) * rs.z, gm.z, bt.z) + v.z);
            v.w = fmaxf(0.f, fmaf((a.w - mu.w) * rs.w, gm.w, bt.w) + v.w);
            if (arr == 0) *(float4*)&x1out[goff] = v;
        }
        *(float4*)&Xs[m][k] = v;
    }
    // stage W tile 128x128
    #pragma unroll
    for (int i = 0; i < 16; ++i) {
        int f4 = i * 256 + tid;
        int idx = f4 * 4;
        int k = idx >> 7, c = idx & 127;
        *(float4*)&Wt[k][c] = *(const float4*)&Wsrc[(size_t)(rowoff + k) * D + c];
    }
    __syncthreads();

    const int tr = tid >> 4;   // 0..15: rows tr*4..+3 and 64+tr*4..+3
    const int tc = tid & 15;   // 0..15: cols tc*4..+3 and 64+tc*4..+3

    float acc[8][8] = {};
    for (int k = 0; k < D; k += 4) {
        float4 a0[4], a1[4], w0[4], w1[4];
        #pragma unroll
        for (int im = 0; im < 4; ++im) {
            a0[im] = *(const float4*)&Xs[tr * 4 + im][k];
            a1[im] = *(const float4*)&Xs[64 + tr * 4 + im][k];
        }
        #pragma unroll
        for (int kk = 0; kk < 4; ++kk) {
            w0[kk] = *(const float4*)&Wt[k + kk][tc * 4];
            w1[kk] = *(const float4*)&Wt[k + kk][64 + tc * 4];
        }
        #pragma unroll
        for (int im = 0; im < 4; ++im) {
            const float* ap0 = (const float*)&a0[im];
            const float* ap1 = (const float*)&a1[im];
            #pragma unroll
            for (int kk = 0; kk < 4; ++kk) {
                const float* wp0 = (const float*)&w0[kk];
                const float* wp1 = (const float*)&w1[kk];
                float av0 = ap0[kk], av1 = ap1[kk];
                #pragma unroll
                for (int jn = 0; jn < 4; ++jn) {
                    acc[im][jn]         = fmaf(av0, wp0[jn], acc[im][jn]);
                    acc[im][jn + 4]     = fmaf(av0, wp1[jn], acc[im][jn + 4]);
                    acc[im + 4][jn]     = fmaf(av1, wp0[jn], acc[im + 4][jn]);
                    acc[im + 4][jn + 4] = fmaf(av1, wp1[jn], acc[im + 4][jn + 4]);
                }
            }
        }
    }

    // epilogue: centers term + bias, then exp2
    const float sgn   = (arr & 1) ? -1.f : 1.f;
    const float scale = (arr < 2) ? -LOG2E : LOG2E;
    float cw0[2][4], cw1[2][4], bias[2][4];
    #pragma unroll
    for (int cg = 0; cg < 2; ++cg)
        #pragma unroll
        for (int jn = 0; jn < 4; ++jn) {
            int c = cg * 64 + tc * 4 + jn;
            cw0[cg][jn] = Wsrc[256 * D + c];
            cw1[cg][jn] = Wsrc[257 * D + c];
            bias[cg][jn] = (arr == 0) ? bf[c] : ((arr == 2) ? bs[c] : 0.f);
        }
    float* obase = out + (size_t)arr * NN * D;
    #pragma unroll
    for (int rg = 0; rg < 2; ++rg)
        #pragma unroll
        for (int im = 0; im < 4; ++im) {
            int n = m0 + rg * 64 + tr * 4 + im;
            float ce0 = centers[2 * n], ce1 = centers[2 * n + 1];
            #pragma unroll
            for (int cg = 0; cg < 2; ++cg) {
                float4 v; float* vp = (float*)&v;
                #pragma unroll
                for (int jn = 0; jn < 4; ++jn) {
                    float t = acc[rg * 4 + im][cg * 4 + jn] + bias[cg][jn]
                            + sgn * fmaf(ce0, cw0[cg][jn], ce1 * cw1[cg][jn]);
                    vp[jn] = __builtin_amdgcn_exp2f(scale * t);
                }
                *(float4*)&obase[(size_t)n * D + cg * 64 + tc * 4] = v;
            }
        }
}

// ---------------------------------------------------------------------------
// Kernel 2: edge aggregation within each 64-agent clique.
//   agg[d][c] = sum_{j!=d} rcp(1+EAf[d]*EBf[j]) * log2(1+EAs[d]*EBs[j]) * ln2
// grid = 128 samples x 4 dst-groups; block 256 = 2 dst-halves x 128 channels.
// Each thread owns 8 (d,c) pairs fully -> no atomics. Emits BN partials.
// ---------------------------------------------------------------------------
__global__ __launch_bounds__(256) void edge_kernel(
    const float* __restrict__ EAf, const float* __restrict__ EBf,
    const float* __restrict__ EAs, const float* __restrict__ EBs,
    float* __restrict__ agg,        // [NN][D]
    float* __restrict__ partials)   // [512][256]: s1[128], s2[128]
{
    const int s = blockIdx.x >> 2;
    const int g = blockIdx.x & 3;
    const int tid = threadIdx.x;
    const int c  = tid & 127;
    const int dh = tid >> 7;
    const int nbase = s * AGENTS;

    __shared__ float Bfs[AGENTS][D];
    __shared__ float Bss[AGENTS][D];

    #pragma unroll
    for (int i = 0; i < 8; ++i) {
        int f4 = i * 256 + tid;
        int idx = f4 * 4;
        int j = idx >> 7, cc = idx & 127;
        *(float4*)&Bfs[j][cc] = *(const float4*)&EBf[(size_t)(nbase + j) * D + cc];
        *(float4*)&Bss[j][cc] = *(const float4*)&EBs[(size_t)(nbase + j) * D + cc];
    }
    __syncthreads();

    const int d0 = g * 16 + dh * 8;
    float eaf[8], eas[8], acc[8];
    #pragma unroll
    for (int i = 0; i < 8; ++i) {
        int n = nbase + d0 + i;
        eaf[i] = EAf[(size_t)n * D + c];
        eas[i] = EAs[(size_t)n * D + c];
        acc[i] = 0.f;
    }

    for (int j = 0; j < AGENTS; ++j) {
        float ebf = Bfs[j][c];
        float ebs = Bss[j][c];
        #pragma unroll
        for (int i = 0; i < 8; ++i) {
            float sg = __builtin_amdgcn_rcpf(1.f + eaf[i] * ebf);
            float lg = __builtin_amdgcn_logf(1.f + eas[i] * ebs);
            acc[i] += sg * lg;
        }
    }

    float s1 = 0.f, s2 = 0.f;
    #pragma unroll
    for (int i = 0; i < 8; ++i) {
        int j = d0 + i;
        float sg = __builtin_amdgcn_rcpf(1.f + eaf[i] * Bfs[j][c]);
        float lg = __builtin_amdgcn_logf(1.f + eas[i] * Bss[j][c]);
        float a = (acc[i] - sg * lg) * LN2;
        agg[(size_t)(nbase + d0 + i) * D + c] = a;
        s1 += a;
        s2 += a * a;
    }

    __syncthreads();               // done reading B tiles; reuse LDS
    if (dh == 1) { Bfs[0][c] = s1; Bss[0][c] = s2; }
    __syncthreads();
    if (dh == 0) {
        s1 += Bfs[0][c];
        s2 += Bss[0][c];
        partials[(size_t)blockIdx.x * 256 + c]       = s1;
        partials[(size_t)blockIdx.x * 256 + 128 + c] = s2;
    }
}

// ---------------------------------------------------------------------------
// Kernel 3: reduce 512 partials -> mu[c], rstd[c].  grid 128 (c), block 256.
// ---------------------------------------------------------------------------
__global__ __launch_bounds__(256) void stats_kernel(
    const float* __restrict__ partials, float* __restrict__ stats)
{
    const int c = blockIdx.x;
    const int t = threadIdx.x;
    float s1 = partials[(size_t)t * 256 + c] + partials[(size_t)(t + 256) * 256 + c];
    float s2 = partials[(size_t)t * 256 + 128 + c] + partials[(size_t)(t + 256) * 256 + 128 + c];
    __shared__ float r1[256], r2[256];
    r1[t] = s1; r2[t] = s2;
    __syncthreads();
    for (int off = 128; off > 0; off >>= 1) {
        if (t < off) { r1[t] += r1[t + off]; r2[t] += r2[t + off]; }
        __syncthreads();
    }
    if (t == 0) {
        float mu = r1[0] * (1.f / NN);
        float var = r2[0] * (1.f / NN) - mu * mu;
        stats[c]     = mu;
        stats[D + c] = rsqrtf(var + EPSF);
    }
}

// ---------------------------------------------------------------------------
// Kernel 4: BN + residual + relu (final layer only).
// ---------------------------------------------------------------------------
__global__ __launch_bounds__(256) void bn_kernel(
    const float* __restrict__ agg, const float* __restrict__ xin,
    const float* __restrict__ stats,
    const float* __restrict__ gamma, const float* __restrict__ beta,
    float* __restrict__ outp)
{
    const int t = blockIdx.x * 256 + threadIdx.x;
    const int n = t >> 5;
    const int c = (t & 31) * 4;
    float4 a  = *(const float4*)&agg[(size_t)n * D + c];
    float4 xv = *(const float4*)&xin[(size_t)n * D + c];
    float4 mu = *(const float4*)&stats[c];
    float4 rs = *(const float4*)&stats[D + c];
    float4 gm = *(const float4*)&gamma[c];
    float4 bt = *(const float4*)&beta[c];
    float4 o;
    o.x = fmaxf(0.f, fmaf((a.x - mu.x) * rs.x, gm.x, bt.x) + xv.x);
    o.y = fmaxf(0.f, fmaf((a.y - mu.y) * rs.y, gm.y, bt.y) + xv.y);
    o.z = fmaxf(0.f, fmaf((a.z - mu.z) * rs.z, gm.z, bt.z) + xv.z);
    o.w = fmaxf(0.f, fmaf((a.w - mu.w) * rs.w, gm.w, bt.w) + xv.w);
    *(float4*)&outp[(size_t)n * D + c] = o;
}

// ---------------------------------------------------------------------------
extern "C" void kernel_launch(void* const* d_in, const int* in_sizes, int n_in,
                              void* d_out, int out_size, void* d_ws, size_t ws_size,
                              hipStream_t stream) {
    const float* x0      = (const float*)d_in[0];
    const float* centers = (const float*)d_in[1];
    // d_in[2], d_in[3]: edge lists — structure is deterministic, unused.
    const float* Wf[2] = { (const float*)d_in[4],  (const float*)d_in[10] };
    const float* bf[2] = { (const float*)d_in[5],  (const float*)d_in[11] };
    const float* Ws[2] = { (const float*)d_in[6],  (const float*)d_in[12] };
    const float* bs[2] = { (const float*)d_in[7],  (const float*)d_in[13] };
    const float* gm[2] = { (const float*)d_in[8],  (const float*)d_in[14] };
    const float* bt[2] = { (const float*)d_in[9],  (const float*)d_in[15] };

    float* ws       = (float*)d_ws;
    const size_t ND = (size_t)NN * D;     // 1048576
    float* AB       = ws;                 // 4*ND floats
    float* agg      = ws + 4 * ND;
    float* x1       = ws + 5 * ND;
    float* partials = ws + 6 * ND;        // 512*256
    float* stats    = partials + 512 * 256;

    float* outp = (float*)d_out;

    // Layer 1
    prep_kernel<<<dim3(256), dim3(256), 0, stream>>>(
        x0, centers, Wf[0], bf[0], Ws[0], bs[0],
        nullptr, nullptr, nullptr, nullptr, nullptr, AB);
    edge_kernel<<<dim3(512), dim3(256), 0, stream>>>(
        AB, AB + ND, AB + 2 * ND, AB + 3 * ND, agg, partials);
    stats_kernel<<<dim3(128), dim3(256), 0, stream>>>(partials, stats);
    // Layer 2 (prep fuses layer-1 BN+residual+relu while staging X; arr==0
    // blocks also write x1 for the final residual)
    prep_kernel<<<dim3(256), dim3(256), 0, stream>>>(
        x0, centers, Wf[1], bf[1], Ws[1], bs[1],
        agg, stats, gm[0], bt[0], x1, AB);
    edge_kernel<<<dim3(512), dim3(256), 0, stream>>>(
        AB, AB + ND, AB + 2 * ND, AB + 3 * ND, agg, partials);
    stats_kernel<<<dim3(128), dim3(256), 0, stream>>>(partials, stats);
    bn_kernel<<<dim3(1024), dim3(256), 0, stream>>>(
        agg, x1, stats, gm[1], bt[1], outp);
}

// Round 4
// 165.213 us; speedup vs baseline: 1.1263x; 1.1263x over previous
//
#include <hip/hip_runtime.h>
#include <hip/hip_bf16.h>

#define NSAMP 128
#define AGENTS 64
#define D 128
#define NN (NSAMP * AGENTS)      // 8192
#define LOG2E 1.44269504088896340736f
#define LN2   0.69314718055994530942f
#define EPSF  1e-5f

typedef __attribute__((ext_vector_type(8))) short short8;
typedef __attribute__((ext_vector_type(4))) float floatx4;

__device__ __forceinline__ float bf2f(unsigned short u) {
    unsigned v = ((unsigned)u) << 16;
    float f; __builtin_memcpy(&f, &v, 4); return f;
}
__device__ __forceinline__ unsigned short f2bf(float f) {
    unsigned x; __builtin_memcpy(&x, &f, 4);
    return (unsigned short)((x + 0x7FFFu + ((x >> 16) & 1u)) >> 16);
}

// ---------------------------------------------------------------------------
// K0: convert x0 -> bf16 Xb, and build transposed bf16 weights
//   WT[layer][arr][c][k] = Wside[k][c], arr: 0=Af(Wf hi) 1=Bf(Wf lo) 2=As 3=Bs
// grid 576: blocks 0..511 x-convert (8 elems/thread), 512..575 weights.
// ---------------------------------------------------------------------------
__global__ __launch_bounds__(256) void cvt_kernel(
    const float* __restrict__ x0,
    const float* __restrict__ Wf1, const float* __restrict__ Ws1,
    const float* __restrict__ Wf2, const float* __restrict__ Ws2,
    unsigned short* __restrict__ Xb, unsigned short* __restrict__ WT)
{
    int b = blockIdx.x;
    if (b < 512) {
        int off = (b * 256 + threadIdx.x) * 8;
        float4 v0 = *(const float4*)&x0[off];
        float4 v1 = *(const float4*)&x0[off + 4];
        short8 s;
        s[0] = (short)f2bf(v0.x); s[1] = (short)f2bf(v0.y);
        s[2] = (short)f2bf(v0.z); s[3] = (short)f2bf(v0.w);
        s[4] = (short)f2bf(v1.x); s[5] = (short)f2bf(v1.y);
        s[6] = (short)f2bf(v1.z); s[7] = (short)f2bf(v1.w);
        *(short8*)&Xb[off] = s;
    } else {
        int wb = b - 512;                       // 0..63
        int rr = wb * 16 + (threadIdx.x >> 4);  // 0..1023 = layer*512+arr*128+c
        int kk = (threadIdx.x & 15) * 8;
        int layer = rr >> 9, rem = rr & 511, arr = rem >> 7, c = rem & 127;
        const float* M = (arr < 2) ? (layer ? Wf2 : Wf1) : (layer ? Ws2 : Ws1);
        int side = arr & 1;                     // 0: rows 0:128, 1: rows 128:256
        short8 s;
        #pragma unroll
        for (int j = 0; j < 8; ++j)
            s[j] = (short)f2bf(M[(size_t)(side * 128 + kk + j) * D + c]);
        *(short8*)&WT[(size_t)(layer * 4 + arr) * 16384 + c * 128 + kk] = s;
    }
}

// ---------------------------------------------------------------------------
// K1: MFMA prep. Per 16-row m-tile, 4 waves = 4 arrays (Af,Bf,As,Bs cols).
// D[m][n] = sum_k Xb[m][k] * WT[arr][n][k]  (16x16x32 bf16 MFMA, K=128)
// Epilogue (fp32 exact): t = D + bias + sgn*(ce0*cw0+ce1*cw1);
//   out = bf16(exp2(scale*t)),  scale=-log2e (f gates), +log2e (s gates).
// No LDS at all; A/B frags load straight from global (b128/lane).
// Verified layouts: A[m=lane&15][k=quad*8+j]; B[k=quad*8+j][n=lane&15];
// C/D: col=lane&15, row=quad*4+reg.
// ---------------------------------------------------------------------------
__global__ __launch_bounds__(256) void prep_mfma(
    const unsigned short* __restrict__ Xb,   // [NN][128] bf16
    const unsigned short* __restrict__ WT,   // [4][128][128] bf16 (this layer)
    const float* __restrict__ centers,       // [NN][2]
    const float* __restrict__ Wf, const float* __restrict__ bf_,
    const float* __restrict__ Ws, const float* __restrict__ bs_,
    unsigned short* __restrict__ out)        // 4 x [NN][128] bf16
{
    const int m0   = blockIdx.x * 16;
    const int wv   = threadIdx.x >> 6;       // arr 0..3
    const int lane = threadIdx.x & 63;
    const int quad = lane >> 4, l16 = lane & 15;

    // A fragments: 4 K-chunks of 32
    short8 a[4];
    const unsigned short* xrow = Xb + (size_t)(m0 + l16) * 128 + quad * 8;
    #pragma unroll
    for (int kc = 0; kc < 4; ++kc) a[kc] = *(const short8*)(xrow + kc * 32);

    // centers for this quad's 4 rows (broadcast loads)
    float ce0[4], ce1[4];
    #pragma unroll
    for (int r = 0; r < 4; ++r) {
        int n = m0 + quad * 4 + r;
        ce0[r] = centers[2 * n]; ce1[r] = centers[2 * n + 1];
    }

    const float sgn   = (wv & 1) ? -1.f : 1.f;
    const float scale = (wv < 2) ? -LOG2E : LOG2E;
    const float* Wsrc = (wv < 2) ? Wf : Ws;
    const float* bias = (wv == 0) ? bf_ : ((wv == 2) ? bs_ : nullptr);
    const unsigned short* Wa = WT + (size_t)wv * 16384;
    unsigned short* ob = out + (size_t)wv * NN * 128;

    for (int nt = 0; nt < 8; ++nt) {
        const int n0 = nt * 16;
        short8 bfr[4];
        const unsigned short* wrow = Wa + (size_t)(n0 + l16) * 128 + quad * 8;
        #pragma unroll
        for (int kc = 0; kc < 4; ++kc) bfr[kc] = *(const short8*)(wrow + kc * 32);

        floatx4 acc = {0.f, 0.f, 0.f, 0.f};
        #pragma unroll
        for (int kc = 0; kc < 4; ++kc)
            acc = __builtin_amdgcn_mfma_f32_16x16x32_bf16(a[kc], bfr[kc], acc, 0, 0, 0);

        const int col = n0 + l16;
        const float cw0 = Wsrc[256 * D + col];
        const float cw1 = Wsrc[257 * D + col];
        const float bv  = bias ? bias[col] : 0.f;
        #pragma unroll
        for (int r = 0; r < 4; ++r) {
            float t = acc[r] + bv + sgn * fmaf(ce0[r], cw0, ce1[r] * cw1);
            ob[(size_t)(m0 + quad * 4 + r) * 128 + col] =
                f2bf(__builtin_amdgcn_exp2f(scale * t));
        }
    }
}

// ---------------------------------------------------------------------------
// K2: edge aggregation within each 64-agent clique (bf16 inputs, fp32 math).
//   agg[d][c] = sum_{j!=d} rcp(1+EAf[d]*EBf[j]) * log2(1+EAs[d]*EBs[j]) * ln2
// grid = 128 samples x 4 dst-groups; block 256 = 2 dst-halves x 128 channels.
// ---------------------------------------------------------------------------
__global__ __launch_bounds__(256) void edge_kernel(
    const unsigned short* __restrict__ EAf, const unsigned short* __restrict__ EBf,
    const unsigned short* __restrict__ EAs, const unsigned short* __restrict__ EBs,
    float* __restrict__ agg,        // [NN][D]
    float* __restrict__ partials)   // [512][256]: s1[128], s2[128]
{
    const int s = blockIdx.x >> 2;
    const int g = blockIdx.x & 3;
    const int tid = threadIdx.x;
    const int c  = tid & 127;
    const int dh = tid >> 7;
    const int nbase = s * AGENTS;

    __shared__ float Bfs[AGENTS][D];
    __shared__ float Bss[AGENTS][D];

    #pragma unroll
    for (int i = 0; i < 4; ++i) {
        int f8 = i * 256 + tid;
        int idx = f8 * 8;
        int j = idx >> 7, cc = idx & 127;
        short8 vf = *(const short8*)&EBf[(size_t)(nbase + j) * D + cc];
        short8 vs = *(const short8*)&EBs[(size_t)(nbase + j) * D + cc];
        float4 f0, f1, s0, s1v;
        f0.x = bf2f((unsigned short)vf[0]); f0.y = bf2f((unsigned short)vf[1]);
        f0.z = bf2f((unsigned short)vf[2]); f0.w = bf2f((unsigned short)vf[3]);
        f1.x = bf2f((unsigned short)vf[4]); f1.y = bf2f((unsigned short)vf[5]);
        f1.z = bf2f((unsigned short)vf[6]); f1.w = bf2f((unsigned short)vf[7]);
        s0.x = bf2f((unsigned short)vs[0]); s0.y = bf2f((unsigned short)vs[1]);
        s0.z = bf2f((unsigned short)vs[2]); s0.w = bf2f((unsigned short)vs[3]);
        s1v.x = bf2f((unsigned short)vs[4]); s1v.y = bf2f((unsigned short)vs[5]);
        s1v.z = bf2f((unsigned short)vs[6]); s1v.w = bf2f((unsigned short)vs[7]);
        *(float4*)&Bfs[j][cc]     = f0;
        *(float4*)&Bfs[j][cc + 4] = f1;
        *(float4*)&Bss[j][cc]     = s0;
        *(float4*)&Bss[j][cc + 4] = s1v;
    }
    __syncthreads();

    const int d0 = g * 16 + dh * 8;
    float eaf[8], eas[8], acc[8];
    #pragma unroll
    for (int i = 0; i < 8; ++i) {
        int n = nbase + d0 + i;
        eaf[i] = bf2f(EAf[(size_t)n * D + c]);
        eas[i] = bf2f(EAs[(size_t)n * D + c]);
        acc[i] = 0.f;
    }

    for (int j = 0; j < AGENTS; ++j) {
        float ebf = Bfs[j][c];
        float ebs = Bss[j][c];
        #pragma unroll
        for (int i = 0; i < 8; ++i) {
            float sg = __builtin_amdgcn_rcpf(1.f + eaf[i] * ebf);
            float lg = __builtin_amdgcn_logf(1.f + eas[i] * ebs);
            acc[i] += sg * lg;
        }
    }

    float s1 = 0.f, s2 = 0.f;
    #pragma unroll
    for (int i = 0; i < 8; ++i) {
        int j = d0 + i;
        float sg = __builtin_amdgcn_rcpf(1.f + eaf[i] * Bfs[j][c]);
        float lg = __builtin_amdgcn_logf(1.f + eas[i] * Bss[j][c]);
        float a = (acc[i] - sg * lg) * LN2;
        agg[(size_t)(nbase + d0 + i) * D + c] = a;
        s1 += a;
        s2 += a * a;
    }

    __syncthreads();               // done reading B tiles; reuse LDS
    if (dh == 1) { Bfs[0][c] = s1; Bss[0][c] = s2; }
    __syncthreads();
    if (dh == 0) {
        s1 += Bfs[0][c];
        s2 += Bss[0][c];
        partials[(size_t)blockIdx.x * 256 + c]       = s1;
        partials[(size_t)blockIdx.x * 256 + 128 + c] = s2;
    }
}

// ---------------------------------------------------------------------------
// K3: reduce 512 partials -> mu[c], rstd[c].  grid 128 (c), block 256.
// ---------------------------------------------------------------------------
__global__ __launch_bounds__(256) void stats_kernel(
    const float* __restrict__ partials, float* __restrict__ stats)
{
    const int c = blockIdx.x;
    const int t = threadIdx.x;
    float s1 = partials[(size_t)t * 256 + c] + partials[(size_t)(t + 256) * 256 + c];
    float s2 = partials[(size_t)t * 256 + 128 + c] + partials[(size_t)(t + 256) * 256 + 128 + c];
    __shared__ float r1[256], r2[256];
    r1[t] = s1; r2[t] = s2;
    __syncthreads();
    for (int off = 128; off > 0; off >>= 1) {
        if (t < off) { r1[t] += r1[t + off]; r2[t] += r2[t + off]; }
        __syncthreads();
    }
    if (t == 0) {
        float mu = r1[0] * (1.f / NN);
        float var = r2[0] * (1.f / NN) - mu * mu;
        stats[c]     = mu;
        stats[D + c] = rsqrtf(var + EPSF);
    }
}

// ---------------------------------------------------------------------------
// K4: BN1 + residual + relu -> x1 (fp32, exact residual path) + Xb (bf16)
// 8 elems/thread, grid 512.
// ---------------------------------------------------------------------------
__global__ __launch_bounds__(256) void bncvt_kernel(
    const float* __restrict__ agg, const float* __restrict__ xin,
    const float* __restrict__ stats,
    const float* __restrict__ gamma, const float* __restrict__ beta,
    float* __restrict__ x1, unsigned short* __restrict__ Xb)
{
    const int t = blockIdx.x * 256 + threadIdx.x;
    const int n = t >> 4;
    const int c = (t & 15) * 8;
    size_t off = (size_t)n * D + c;
    float v[8]; short8 s;
    #pragma unroll
    for (int h = 0; h < 2; ++h) {
        float4 a  = *(const float4*)&agg[off + h * 4];
        float4 xv = *(const float4*)&xin[off + h * 4];
        float4 mu = *(const float4*)&stats[c + h * 4];
        float4 rs = *(const float4*)&stats[D + c + h * 4];
        float4 gm = *(const float4*)&gamma[c + h * 4];
        float4 bt = *(const float4*)&beta[c + h * 4];
        v[h*4+0] = fmaxf(0.f, fmaf((a.x - mu.x) * rs.x, gm.x, bt.x) + xv.x);
        v[h*4+1] = fmaxf(0.f, fmaf((a.y - mu.y) * rs.y, gm.y, bt.y) + xv.y);
        v[h*4+2] = fmaxf(0.f, fmaf((a.z - mu.z) * rs.z, gm.z, bt.z) + xv.z);
        v[h*4+3] = fmaxf(0.f, fmaf((a.w - mu.w) * rs.w, gm.w, bt.w) + xv.w);
    }
    *(float4*)&x1[off]     = *(float4*)&v[0];
    *(float4*)&x1[off + 4] = *(float4*)&v[4];
    #pragma unroll
    for (int e = 0; e < 8; ++e) s[e] = (short)f2bf(v[e]);
    *(short8*)&Xb[off] = s;
}

// ---------------------------------------------------------------------------
// K5: final BN + residual + relu -> d_out (fp32)
// ---------------------------------------------------------------------------
__global__ __launch_bounds__(256) void bn_kernel(
    const float* __restrict__ agg, const float* __restrict__ xin,
    const float* __restrict__ stats,
    const float* __restrict__ gamma, const float* __restrict__ beta,
    float* __restrict__ outp)
{
    const int t = blockIdx.x * 256 + threadIdx.x;
    const int n = t >> 5;
    const int c = (t & 31) * 4;
    float4 a  = *(const float4*)&agg[(size_t)n * D + c];
    float4 xv = *(const float4*)&xin[(size_t)n * D + c];
    float4 mu = *(const float4*)&stats[c];
    float4 rs = *(const float4*)&stats[D + c];
    float4 gm = *(const float4*)&gamma[c];
    float4 bt = *(const float4*)&beta[c];
    float4 o;
    o.x = fmaxf(0.f, fmaf((a.x - mu.x) * rs.x, gm.x, bt.x) + xv.x);
    o.y = fmaxf(0.f, fmaf((a.y - mu.y) * rs.y, gm.y, bt.y) + xv.y);
    o.z = fmaxf(0.f, fmaf((a.z - mu.z) * rs.z, gm.z, bt.z) + xv.z);
    o.w = fmaxf(0.f, fmaf((a.w - mu.w) * rs.w, gm.w, bt.w) + xv.w);
    *(float4*)&outp[(size_t)n * D + c] = o;
}

// ---------------------------------------------------------------------------
extern "C" void kernel_launch(void* const* d_in, const int* in_sizes, int n_in,
                              void* d_out, int out_size, void* d_ws, size_t ws_size,
                              hipStream_t stream) {
    const float* x0      = (const float*)d_in[0];
    const float* centers = (const float*)d_in[1];
    // d_in[2], d_in[3]: edge lists — clique structure is deterministic, unused.
    const float* Wf[2] = { (const float*)d_in[4],  (const float*)d_in[10] };
    const float* bf[2] = { (const float*)d_in[5],  (const float*)d_in[11] };
    const float* Ws[2] = { (const float*)d_in[6],  (const float*)d_in[12] };
    const float* bs[2] = { (const float*)d_in[7],  (const float*)d_in[13] };
    const float* gm[2] = { (const float*)d_in[8],  (const float*)d_in[14] };
    const float* bt[2] = { (const float*)d_in[9],  (const float*)d_in[15] };

    const size_t ND = (size_t)NN * D;              // 1048576
    unsigned short* ws_u = (unsigned short*)d_ws;
    unsigned short* Xb = ws_u;                     // ND bf16
    unsigned short* WT = ws_u + ND;                // 2 layers x 65536 bf16
    unsigned short* AB = WT + 2 * 65536;           // 4*ND bf16
    float* fbase    = (float*)(AB + 4 * ND);       // 16B-aligned
    float* agg      = fbase;                       // ND
    float* x1       = fbase + ND;                  // ND
    float* partials = fbase + 2 * ND;              // 512*256
    float* stats    = partials + 512 * 256;        // 256

    float* outp = (float*)d_out;

    // convert x0 -> bf16, build transposed bf16 weights for both layers
    cvt_kernel<<<dim3(576), dim3(256), 0, stream>>>(
        x0, Wf[0], Ws[0], Wf[1], Ws[1], Xb, WT);

    // Layer 1
    prep_mfma<<<dim3(512), dim3(256), 0, stream>>>(
        Xb, WT, centers, Wf[0], bf[0], Ws[0], bs[0], AB);
    edge_kernel<<<dim3(512), dim3(256), 0, stream>>>(
        AB, AB + ND, AB + 2 * ND, AB + 3 * ND, agg, partials);
    stats_kernel<<<dim3(128), dim3(256), 0, stream>>>(partials, stats);
    bncvt_kernel<<<dim3(512), dim3(256), 0, stream>>>(
        agg, x0, stats, gm[0], bt[0], x1, Xb);

    // Layer 2
    prep_mfma<<<dim3(512), dim3(256), 0, stream>>>(
        Xb, WT + 65536, centers, Wf[1], bf[1], Ws[1], bs[1], AB);
    edge_kernel<<<dim3(512), dim3(256), 0, stream>>>(
        AB, AB + ND, AB + 2 * ND, AB + 3 * ND, agg, partials);
    stats_kernel<<<dim3(128), dim3(256), 0, stream>>>(partials, stats);
    bn_kernel<<<dim3(1024), dim3(256), 0, stream>>>(
        agg, x1, stats, gm[1], bt[1], outp);
}

// Round 5
// 163.140 us; speedup vs baseline: 1.1406x; 1.0127x over previous
//
#include <hip/hip_runtime.h>
#include <hip/hip_bf16.h>

#define NSAMP 128
#define AGENTS 64
#define D 128
#define NN (NSAMP * AGENTS)      // 8192
#define LOG2E 1.44269504088896340736f
#define LN2   0.69314718055994530942f
#define EPSF  1e-5f

typedef __attribute__((ext_vector_type(8))) short short8;
typedef __attribute__((ext_vector_type(4))) float floatx4;

__device__ __forceinline__ float u2f(unsigned v) {
    float f; __builtin_memcpy(&f, &v, 4); return f;
}
__device__ __forceinline__ unsigned short f2bf(float f) {
    unsigned x; __builtin_memcpy(&x, &f, 4);
    return (unsigned short)((x + 0x7FFFu + ((x >> 16) & 1u)) >> 16);
}

// ---------------------------------------------------------------------------
// K0: convert x0 -> bf16 Xb; build transposed bf16 weights WT; zero stats acc.
//   WT[layer][arr][c][k] = Wside[k][c]; arr: 0=Af 1=Bf 2=As 3=Bs
// grid 577: 0..511 x-convert (8/thread), 512..575 weights, 576 zeros sacc.
// ---------------------------------------------------------------------------
__global__ __launch_bounds__(256) void cvt_kernel(
    const float* __restrict__ x0,
    const float* __restrict__ Wf1, const float* __restrict__ Ws1,
    const float* __restrict__ Wf2, const float* __restrict__ Ws2,
    unsigned short* __restrict__ Xb, unsigned short* __restrict__ WT,
    float* __restrict__ sacc)       // [2][2][128] zeroed
{
    int b = blockIdx.x;
    if (b < 512) {
        int off = (b * 256 + threadIdx.x) * 8;
        float4 v0 = *(const float4*)&x0[off];
        float4 v1 = *(const float4*)&x0[off + 4];
        short8 s;
        s[0] = (short)f2bf(v0.x); s[1] = (short)f2bf(v0.y);
        s[2] = (short)f2bf(v0.z); s[3] = (short)f2bf(v0.w);
        s[4] = (short)f2bf(v1.x); s[5] = (short)f2bf(v1.y);
        s[6] = (short)f2bf(v1.z); s[7] = (short)f2bf(v1.w);
        *(short8*)&Xb[off] = s;
    } else if (b < 576) {
        int wb = b - 512;                       // 0..63
        int rr = wb * 16 + (threadIdx.x >> 4);  // layer*512 + arr*128 + c
        int kk = (threadIdx.x & 15) * 8;
        int layer = rr >> 9, rem = rr & 511, arr = rem >> 7, c = rem & 127;
        const float* M = (arr < 2) ? (layer ? Wf2 : Wf1) : (layer ? Ws2 : Ws1);
        int side = arr & 1;                     // 0: W rows 0:128 (dst), 1: 128:256 (src)
        short8 s;
        #pragma unroll
        for (int j = 0; j < 8; ++j)
            s[j] = (short)f2bf(M[(size_t)(side * 128 + kk + j) * D + c]);
        *(short8*)&WT[(size_t)(layer * 4 + arr) * 16384 + c * 128 + kk] = s;
    } else {
        sacc[threadIdx.x]       = 0.f;
        sacc[256 + threadIdx.x] = 0.f;
    }
}

// ---------------------------------------------------------------------------
// K1: fused prep (MFMA) + edge aggregation. One block = (sample, 16 dst rows).
// Phase A: MFMA gates -> LDS. EB (src gates, all 64 rows) packed bf16 pairs
//   (low=EBf, high=EBs) in one u32; EA (dst gates, 16 rows) fp32.
//   Verified layouts: A[m=lane&15][k=quad*8+j]; B[k][n=lane&15] from WT[n][k];
//   C/D col=lane&15, row=quad*4+reg.
// Phase B: agg[d][c] = sum_{j!=d} rcp(1+EAf*EBf) * log2(1+EAs*EBs) * ln2.
// Stats: per-block s1/s2 per channel -> atomicAdd into sacc (zeroed by K0).
// ---------------------------------------------------------------------------
__global__ __launch_bounds__(256) void prep_edge(
    const unsigned short* __restrict__ Xb,   // [NN][128] bf16
    const unsigned short* __restrict__ WT,   // [4][128][128] bf16, this layer
    const float* __restrict__ centers,       // [NN][2]
    const float* __restrict__ Wf, const float* __restrict__ bf_,
    const float* __restrict__ Ws, const float* __restrict__ bs_,
    float* __restrict__ agg,                 // [NN][D] fp32
    float* __restrict__ sacc)                // [2][128] s1,s2
{
    const int s = blockIdx.x >> 2, g = blockIdx.x & 3;
    const int nbase = s * AGENTS;
    const int tid = threadIdx.x, wv = tid >> 6, lane = tid & 63;
    const int quad = lane >> 4, l16 = lane & 15;

    __shared__ float        EAls[2][16][132];   // [0]=EAf [1]=EAs, dst rows
    __shared__ unsigned int EBpk[64][132];      // low16=EBf, high16=EBs (bf16)

    // hoist src-side W fragments (Bf=arr1, Bs=arr3) for this wave's 2 ntiles
    short8 wBf[2][4], wBs[2][4];
    float cwf0[2], cwf1[2], cws0[2], cws1[2], bfv[2], bsv[2];
    #pragma unroll
    for (int p = 0; p < 2; ++p) {
        const int col = wv * 32 + p * 16 + l16;
        const unsigned short* w1 = WT + (size_t)1 * 16384 + (size_t)col * 128 + quad * 8;
        const unsigned short* w3 = WT + (size_t)3 * 16384 + (size_t)col * 128 + quad * 8;
        #pragma unroll
        for (int kc = 0; kc < 4; ++kc) {
            wBf[p][kc] = *(const short8*)(w1 + kc * 32);
            wBs[p][kc] = *(const short8*)(w3 + kc * 32);
        }
        cwf0[p] = Wf[256 * D + col]; cwf1[p] = Wf[257 * D + col];
        cws0[p] = Ws[256 * D + col]; cws1[p] = Ws[257 * D + col];
        bfv[p] = bf_[col]; bsv[p] = bs_[col];
    }

    for (int m = 0; m < 4; ++m) {
        short8 a[4];
        const unsigned short* xr = Xb + (size_t)(nbase + m * 16 + l16) * 128 + quad * 8;
        #pragma unroll
        for (int kc = 0; kc < 4; ++kc) a[kc] = *(const short8*)(xr + kc * 32);
        float ce0[4], ce1[4];
        #pragma unroll
        for (int r = 0; r < 4; ++r) {
            int n = nbase + m * 16 + quad * 4 + r;
            ce0[r] = centers[2 * n]; ce1[r] = centers[2 * n + 1];
        }
        #pragma unroll
        for (int p = 0; p < 2; ++p) {
            floatx4 aF = {0.f,0.f,0.f,0.f}, aS = {0.f,0.f,0.f,0.f};
            #pragma unroll
            for (int kc = 0; kc < 4; ++kc) {
                aF = __builtin_amdgcn_mfma_f32_16x16x32_bf16(a[kc], wBf[p][kc], aF, 0,0,0);
                aS = __builtin_amdgcn_mfma_f32_16x16x32_bf16(a[kc], wBs[p][kc], aS, 0,0,0);
            }
            const int col = wv * 32 + p * 16 + l16;
            #pragma unroll
            for (int r = 0; r < 4; ++r) {
                float ctf = fmaf(ce0[r], cwf0[p], ce1[r] * cwf1[p]);
                float cts = fmaf(ce0[r], cws0[p], ce1[r] * cws1[p]);
                unsigned uf = (unsigned)f2bf(__builtin_amdgcn_exp2f(-LOG2E * (aF[r] - ctf)));
                unsigned us = (unsigned)f2bf(__builtin_amdgcn_exp2f( LOG2E * (aS[r] - cts)));
                EBpk[m * 16 + quad * 4 + r][col] = uf | (us << 16);
            }
        }
        if (m == g) {   // dst rows == src mtile g: also compute EA gates
            #pragma unroll
            for (int p = 0; p < 2; ++p) {
                const int col = wv * 32 + p * 16 + l16;
                const unsigned short* w0 = WT + (size_t)col * 128 + quad * 8;
                const unsigned short* w2 = WT + (size_t)2 * 16384 + (size_t)col * 128 + quad * 8;
                floatx4 aF = {0.f,0.f,0.f,0.f}, aS = {0.f,0.f,0.f,0.f};
                #pragma unroll
                for (int kc = 0; kc < 4; ++kc) {
                    short8 f0 = *(const short8*)(w0 + kc * 32);
                    short8 f2 = *(const short8*)(w2 + kc * 32);
                    aF = __builtin_amdgcn_mfma_f32_16x16x32_bf16(a[kc], f0, aF, 0,0,0);
                    aS = __builtin_amdgcn_mfma_f32_16x16x32_bf16(a[kc], f2, aS, 0,0,0);
                }
                #pragma unroll
                for (int r = 0; r < 4; ++r) {
                    float ctf = fmaf(ce0[r], cwf0[p], ce1[r] * cwf1[p]);
                    float cts = fmaf(ce0[r], cws0[p], ce1[r] * cws1[p]);
                    EAls[0][quad * 4 + r][col] =
                        __builtin_amdgcn_exp2f(-LOG2E * (aF[r] + ctf + bfv[p]));
                    EAls[1][quad * 4 + r][col] =
                        __builtin_amdgcn_exp2f( LOG2E * (aS[r] + cts + bsv[p]));
                }
            }
        }
    }
    __syncthreads();

    // Phase B: edge aggregation. thread = (c, dh); 8 dst rows each.
    const int c = tid & 127, dh = tid >> 7;
    float eaf[8], eas[8], acc[8];
    #pragma unroll
    for (int i = 0; i < 8; ++i) {
        eaf[i] = EAls[0][dh * 8 + i][c];
        eas[i] = EAls[1][dh * 8 + i][c];
        acc[i] = 0.f;
    }
    for (int j = 0; j < 64; ++j) {
        unsigned pk = EBpk[j][c];
        float ebf = u2f(pk << 16);
        float ebs = u2f(pk & 0xFFFF0000u);
        #pragma unroll
        for (int i = 0; i < 8; ++i) {
            float sg = __builtin_amdgcn_rcpf(fmaf(eaf[i], ebf, 1.f));
            float lg = __builtin_amdgcn_logf(fmaf(eas[i], ebs, 1.f));
            acc[i] = fmaf(sg, lg, acc[i]);
        }
    }
    float s1 = 0.f, s2 = 0.f;
    #pragma unroll
    for (int i = 0; i < 8; ++i) {
        int dl = g * 16 + dh * 8 + i;           // local row of dst in 0..63
        unsigned pk = EBpk[dl][c];
        float ebf = u2f(pk << 16);
        float ebs = u2f(pk & 0xFFFF0000u);
        float sg = __builtin_amdgcn_rcpf(fmaf(eaf[i], ebf, 1.f));
        float lg = __builtin_amdgcn_logf(fmaf(eas[i], ebs, 1.f));
        float a = (acc[i] - sg * lg) * LN2;     // exact self-cancel (same inputs)
        agg[(size_t)(nbase + dl) * D + c] = a;
        s1 += a; s2 += a * a;
    }
    __syncthreads();                            // EB/EA reads done; reuse LDS
    if (dh == 1) { EAls[0][0][c] = s1; EAls[0][1][c] = s2; }
    __syncthreads();
    if (dh == 0) {
        atomicAdd(&sacc[c],       s1 + EAls[0][0][c]);
        atomicAdd(&sacc[128 + c], s2 + EAls[0][1][c]);
    }
}

// ---------------------------------------------------------------------------
// K2: BN(+residual+relu) from raw sums; writes fp32 x1 and bf16 Xb.
// 8 elems/thread, grid 512.
// ---------------------------------------------------------------------------
__global__ __launch_bounds__(256) void bncvt_kernel(
    const float* __restrict__ agg, const float* __restrict__ xin,
    const float* __restrict__ sacc,
    const float* __restrict__ gamma, const float* __restrict__ beta,
    float* __restrict__ x1, unsigned short* __restrict__ Xb)
{
    const int t = blockIdx.x * 256 + threadIdx.x;
    const int n = t >> 4;
    const int c = (t & 15) * 8;
    size_t off = (size_t)n * D + c;
    const float inv = 1.f / NN;
    float v[8]; short8 sv;
    #pragma unroll
    for (int h = 0; h < 2; ++h) {
        float4 a  = *(const float4*)&agg[off + h * 4];
        float4 xv = *(const float4*)&xin[off + h * 4];
        float4 s1 = *(const float4*)&sacc[c + h * 4];
        float4 s2 = *(const float4*)&sacc[128 + c + h * 4];
        float4 gm = *(const float4*)&gamma[c + h * 4];
        float4 bt = *(const float4*)&beta[c + h * 4];
        float mu, var, rs;
        mu = s1.x * inv; var = s2.x * inv - mu * mu; rs = rsqrtf(var + EPSF);
        v[h*4+0] = fmaxf(0.f, fmaf((a.x - mu) * rs, gm.x, bt.x) + xv.x);
        mu = s1.y * inv; var = s2.y * inv - mu * mu; rs = rsqrtf(var + EPSF);
        v[h*4+1] = fmaxf(0.f, fmaf((a.y - mu) * rs, gm.y, bt.y) + xv.y);
        mu = s1.z * inv; var = s2.z * inv - mu * mu; rs = rsqrtf(var + EPSF);
        v[h*4+2] = fmaxf(0.f, fmaf((a.z - mu) * rs, gm.z, bt.z) + xv.z);
        mu = s1.w * inv; var = s2.w * inv - mu * mu; rs = rsqrtf(var + EPSF);
        v[h*4+3] = fmaxf(0.f, fmaf((a.w - mu) * rs, gm.w, bt.w) + xv.w);
    }
    *(float4*)&x1[off]     = *(float4*)&v[0];
    *(float4*)&x1[off + 4] = *(float4*)&v[4];
    #pragma unroll
    for (int e = 0; e < 8; ++e) sv[e] = (short)f2bf(v[e]);
    *(short8*)&Xb[off] = sv;
}

// ---------------------------------------------------------------------------
// K3: final BN + residual + relu -> d_out (fp32), from raw sums. grid 512.
// ---------------------------------------------------------------------------
__global__ __launch_bounds__(256) void bn_kernel(
    const float* __restrict__ agg, const float* __restrict__ xin,
    const float* __restrict__ sacc,
    const float* __restrict__ gamma, const float* __restrict__ beta,
    float* __restrict__ outp)
{
    const int t = blockIdx.x * 256 + threadIdx.x;
    const int n = t >> 4;
    const int c = (t & 15) * 8;
    size_t off = (size_t)n * D + c;
    const float inv = 1.f / NN;
    float v[8];
    #pragma unroll
    for (int h = 0; h < 2; ++h) {
        float4 a  = *(const float4*)&agg[off + h * 4];
        float4 xv = *(const float4*)&xin[off + h * 4];
        float4 s1 = *(const float4*)&sacc[c + h * 4];
        float4 s2 = *(const float4*)&sacc[128 + c + h * 4];
        float4 gm = *(const float4*)&gamma[c + h * 4];
        float4 bt = *(const float4*)&beta[c + h * 4];
        float mu, var, rs;
        mu = s1.x * inv; var = s2.x * inv - mu * mu; rs = rsqrtf(var + EPSF);
        v[h*4+0] = fmaxf(0.f, fmaf((a.x - mu) * rs, gm.x, bt.x) + xv.x);
        mu = s1.y * inv; var = s2.y * inv - mu * mu; rs = rsqrtf(var + EPSF);
        v[h*4+1] = fmaxf(0.f, fmaf((a.y - mu) * rs, gm.y, bt.y) + xv.y);
        mu = s1.z * inv; var = s2.z * inv - mu * mu; rs = rsqrtf(var + EPSF);
        v[h*4+2] = fmaxf(0.f, fmaf((a.z - mu) * rs, gm.z, bt.z) + xv.z);
        mu = s1.w * inv; var = s2.w * inv - mu * mu; rs = rsqrtf(var + EPSF);
        v[h*4+3] = fmaxf(0.f, fmaf((a.w - mu) * rs, gm.w, bt.w) + xv.w);
    }
    *(float4*)&outp[off]     = *(float4*)&v[0];
    *(float4*)&outp[off + 4] = *(float4*)&v[4];
}

// ---------------------------------------------------------------------------
extern "C" void kernel_launch(void* const* d_in, const int* in_sizes, int n_in,
                              void* d_out, int out_size, void* d_ws, size_t ws_size,
                              hipStream_t stream) {
    const float* x0      = (const float*)d_in[0];
    const float* centers = (const float*)d_in[1];
    // d_in[2], d_in[3]: edge lists — clique structure is deterministic, unused.
    const float* Wf[2] = { (const float*)d_in[4],  (const float*)d_in[10] };
    const float* bf[2] = { (const float*)d_in[5],  (const float*)d_in[11] };
    const float* Ws[2] = { (const float*)d_in[6],  (const float*)d_in[12] };
    const float* bs[2] = { (const float*)d_in[7],  (const float*)d_in[13] };
    const float* gm[2] = { (const float*)d_in[8],  (const float*)d_in[14] };
    const float* bt[2] = { (const float*)d_in[9],  (const float*)d_in[15] };

    const size_t ND = (size_t)NN * D;              // 1048576
    unsigned short* ws_u = (unsigned short*)d_ws;
    unsigned short* Xb = ws_u;                     // ND bf16
    unsigned short* WT = ws_u + ND;                // 2 x 65536 bf16
    float* fbase = (float*)(WT + 2 * 65536);       // 16B-aligned
    float* agg   = fbase;                          // ND
    float* x1    = fbase + ND;                     // ND
    float* sacc  = fbase + 2 * ND;                 // 2 layers x 256

    float* outp = (float*)d_out;

    cvt_kernel<<<dim3(577), dim3(256), 0, stream>>>(
        x0, Wf[0], Ws[0], Wf[1], Ws[1], Xb, WT, sacc);

    // Layer 1
    prep_edge<<<dim3(512), dim3(256), 0, stream>>>(
        Xb, WT, centers, Wf[0], bf[0], Ws[0], bs[0], agg, sacc);
    bncvt_kernel<<<dim3(512), dim3(256), 0, stream>>>(
        agg, x0, sacc, gm[0], bt[0], x1, Xb);

    // Layer 2
    prep_edge<<<dim3(512), dim3(256), 0, stream>>>(
        Xb, WT + 65536, centers, Wf[1], bf[1], Ws[1], bs[1], agg, sacc + 256);
    bn_kernel<<<dim3(512), dim3(256), 0, stream>>>(
        agg, x1, sacc + 256, gm[1], bt[1], outp);
}